// Round 6
// baseline (988.271 us; speedup 1.0000x reference)
//
#include <hip/hip_runtime.h>

typedef unsigned short u16;
typedef unsigned int u32;
typedef __attribute__((ext_vector_type(8))) short bf16x8;   // 8 bf16 in 4 VGPRs
typedef __attribute__((ext_vector_type(4))) float f32x4;
typedef __attribute__((ext_vector_type(4))) u32 u32x4;

#define NROWS 65536
#define CCH 128
#define PE ((size_t)65537*128)     // elems per pool buffer (N+1 rows)

__device__ __forceinline__ float bf2f(u16 x){ u32 u=((u32)x)<<16; return __builtin_bit_cast(float,u); }
__device__ __forceinline__ u16 f2bf(float f){ u32 u=__builtin_bit_cast(u32,f); u += 0x7fffu + ((u>>16)&1u); return (u16)(u>>16); }
__device__ __forceinline__ float lrelu(float v){ return v>=0.f? v : 0.01f*v; }
__device__ __forceinline__ u32 fenc(float f){ u32 u=__builtin_bit_cast(u32,f); return (u & 0x80000000u) ? ~u : (u | 0x80000000u); }
__device__ __forceinline__ float fdec(u32 u){ u32 b = (u & 0x80000000u) ? (u ^ 0x80000000u) : ~u; return __builtin_bit_cast(float,b); }

// ---------------------------------------------------------------- weight transpose (f32 -> bf16 [n][k])
__global__ __launch_bounds__(256) void prep_transpose(
    const float* __restrict__ lw, const float* __restrict__ ww, const float* __restrict__ pj,
    const float* __restrict__ fw, const float* __restrict__ c1, const float* __restrict__ c2,
    u16* __restrict__ WT)
{
  int i = blockIdx.x*256 + threadIdx.x;   // grid exactly 1081344 threads
  float v;
  if (i < 49152)      { int j=i;        int m=j>>14,e=j&16383,n=e>>7,k=e&127; v=lw[(m<<14)+(k<<7)+n]; }
  else if (i < 98304) { int j=i-49152;  int m=j>>14,e=j&16383,n=e>>7,k=e&127; v=ww[(m<<14)+(k<<7)+n]; }
  else if (i < 163840){ int j=i-98304;  int m=j>>14,e=j&16383,n=e>>7,k=e&127; v=pj[(m<<14)+(k<<7)+n]; }
  else if (i < 196608){ int j=i-163840; int n=j>>8, k=j&255;                  v=fw[(k<<7)+n]; }
  else if (i < 638976){ int j=i-196608; int m=j>>14,e=j&16383,n=e>>7,k=e&127; v=c1[(m<<14)+(k<<7)+n]; }
  else                { int j=i-638976; int m=j>>14,e=j&16383,n=e>>7,k=e&127; v=c2[(m<<14)+(k<<7)+n]; }
  WT[i]=f2bf(v);
}

// ---------------------------------------------------------------- neighbor transpose [row][27] -> [tap][row]
__global__ __launch_bounds__(256) void nbrT_k(const int* __restrict__ nbr, int* __restrict__ nbrT){
  __shared__ int s[64*27];
  int b = blockIdx.x;                       // 1024 blocks
  for (int i=threadIdx.x; i<64*27; i+=256) s[i] = nbr[b*64*27 + i];
  __syncthreads();
  for (int i=threadIdx.x; i<64*27; i+=256){
    int tap=i>>6, row=i&63;
    nbrT[(size_t)tap*NROWS + b*64 + row] = s[row*27 + tap];
  }
}

// ---------------------------------------------------------------- CSR build
__global__ __launch_bounds__(256) void hist_k(const int* __restrict__ cl, int* __restrict__ cnt){
  int i = blockIdx.x*256 + threadIdx.x;           // 3*N
  int l = i>>16;
  atomicAdd(&cnt[l*1024 + cl[i]], 1);
}
__global__ __launch_bounds__(1024) void scan_k(const int* __restrict__ cnt, int* __restrict__ starts, int* __restrict__ cur){
  int l = blockIdx.x, t = threadIdx.x;
  __shared__ int s[1024];
  int v = cnt[l*1024+t];
  s[t]=v; __syncthreads();
  for (int off=1; off<1024; off<<=1){
    int u_ = (t>=off) ? s[t-off] : 0;
    __syncthreads();
    s[t] += u_;
    __syncthreads();
  }
  int incl=s[t], excl=incl-v;
  starts[l*1025+t]=excl;
  if (t==1023) starts[l*1025+1024]=incl;
  cur[l*1024+t]=excl;
}
__global__ __launch_bounds__(256) void scatter_k(const int* __restrict__ cl, int* __restrict__ cur, int* __restrict__ order){
  int i = blockIdx.x*256 + threadIdx.x;           // 3*N
  int l = i>>16;
  int c = cl[i];
  int p = atomicAdd(&cur[l*1024+c], 1);
  order[l*65536 + p] = i & 65535;
}

// ---------------------------------------------------------------- phase-1 GEMM: A=feat (f32) staged once, 7 B-passes
struct BS7 { const u16* BT[7]; u16* out[7]; float* stats[7]; };

__global__ __launch_bounds__(256,2) void gemm_feat7(const float* __restrict__ feat, BS7 p)
{
  const int tid=threadIdx.x, lane=tid&63, quad=lane>>4, l15=lane&15;
  const int w=tid>>6, rh=w>>1, chq=w&1;
  const int row0=blockIdx.x*128;

  __shared__ __align__(16) u16 ldsA[128*136];
  __shared__ float cs[256];

  #pragma unroll
  for (int it=0; it<8; ++it){
    int row = it*16 + (tid>>4), chn = tid&15;
    const float* Af = feat + (size_t)(row0+row)*CCH + chn*8;
    float4 lo = *(const float4*)(Af);
    float4 hi = *(const float4*)(Af+4);
    u32x4 d;
    d[0]=(u32)f2bf(lo.x)|((u32)f2bf(lo.y)<<16);
    d[1]=(u32)f2bf(lo.z)|((u32)f2bf(lo.w)<<16);
    d[2]=(u32)f2bf(hi.x)|((u32)f2bf(hi.y)<<16);
    d[3]=(u32)f2bf(hi.z)|((u32)f2bf(hi.w)<<16);
    *(u32x4*)(&ldsA[row*136 + chn*8]) = d;
  }
  __syncthreads();

  #pragma unroll 1
  for (int y=0; y<7; ++y){
    const u16* Bb = p.BT[y];
    f32x4 acc[4][4];
    #pragma unroll
    for (int a_=0;a_<4;++a_)
      #pragma unroll
      for (int b_=0;b_<4;++b_) acc[a_][b_]=(f32x4){0.f,0.f,0.f,0.f};
    #pragma unroll
    for (int ks=0; ks<4; ++ks){
      bf16x8 af[4], bfv[4];
      #pragma unroll
      for (int mb=0;mb<4;++mb)
        af[mb]=*(const bf16x8*)(&ldsA[(rh*64+mb*16+l15)*136 + ks*32 + quad*8]);
      #pragma unroll
      for (int nb=0;nb<4;++nb)
        bfv[nb]=*(const bf16x8*)(Bb + (size_t)(chq*64+nb*16+l15)*CCH + ks*32 + quad*8);
      #pragma unroll
      for (int mb=0;mb<4;++mb)
        #pragma unroll
        for (int nb=0;nb<4;++nb)
          acc[mb][nb]=__builtin_amdgcn_mfma_f32_16x16x32_bf16(af[mb],bfv[nb],acc[mb][nb],0,0,0);
    }
    u16* O = p.out[y];
    #pragma unroll
    for (int mb=0;mb<4;++mb){
      int rbase=row0+rh*64+mb*16+quad*4;
      #pragma unroll
      for (int e=0;e<4;++e)
        #pragma unroll
        for (int nb=0;nb<4;++nb)
          O[(size_t)(rbase+e)*CCH + chq*64+nb*16+l15]=f2bf(acc[mb][nb][e]);
    }
    __syncthreads();
    cs[tid]=0.f;
    __syncthreads();
    #pragma unroll
    for (int nb=0;nb<4;++nb){
      float s=0.f,s2=0.f;
      #pragma unroll
      for (int mb=0;mb<4;++mb)
        #pragma unroll
        for (int e=0;e<4;++e){ float v=acc[mb][nb][e]; s+=v; s2+=v*v; }
      s += __shfl_xor(s,16);  s += __shfl_xor(s,32);
      s2+= __shfl_xor(s2,16); s2+= __shfl_xor(s2,32);
      if (lane<16){
        int col=chq*64+nb*16+l15;
        atomicAdd(&cs[col],s); atomicAdd(&cs[128+col],s2);
      }
    }
    __syncthreads();
    atomicAdd(&p.stats[y][tid], cs[tid]);
  }
}

// ---------------------------------------------------------------- per-cluster sums of lrelu(bn(praw)) -> segmean (bf16)
__global__ __launch_bounds__(256) void seg_sum_all(
    const u16* __restrict__ pbase, const float* __restrict__ stats,
    const float* __restrict__ gamma, const float* __restrict__ beta,
    const int* __restrict__ starts, const int* __restrict__ order,
    u16* __restrict__ segmean)
{
  __shared__ float sc[128], sh[128], ssum[128];
  const int tid=threadIdx.x, b=blockIdx.x;
  const int level=b>>10, seg=b&1023;
  const u16* praw = pbase + (size_t)level*PE;
  const float* st = stats + level*256;
  if (tid<128){
    float s=st[tid], s2=st[128+tid];
    float mean=s*(1.0f/65536.0f);
    float var =s2*(1.0f/65536.0f)-mean*mean;
    float rstd=rsqrtf(var+1e-5f);
    float scv =gamma[level*128+tid]*rstd;
    sc[tid]=scv; sh[tid]=beta[level*128+tid]-mean*scv;
    ssum[tid]=0.f;
  }
  __syncthreads();
  const int s0=starts[level*1025+seg], en=starts[level*1025+seg+1];
  const int c2=tid&63, half=tid>>6;
  const int* ord = order + level*65536;
  const float sc0=sc[2*c2], sc1=sc[2*c2+1], sh0=sh[2*c2], sh1=sh[2*c2+1];
  float a0=0.f, a1=0.f;
  for (int m=s0+half; m<en; m+=4){
    int r=ord[m];
    u32 x=*(const u32*)(praw + (size_t)r*CCH + 2*c2);
    a0 += lrelu(sc0*bf2f((u16)(x&0xffffu))+sh0);
    a1 += lrelu(sc1*bf2f((u16)(x>>16))    +sh1);
  }
  atomicAdd(&ssum[2*c2],a0); atomicAdd(&ssum[2*c2+1],a1);
  __syncthreads();
  if (tid<128){
    float inv = 1.0f/fmaxf((float)(en-s0),1.0f);
    segmean[(size_t)b*128+tid]=f2bf(ssum[tid]*inv);
  }
}

// ---------------------------------------------------------------- segmean @ w_w -> segW (bf16), 24 blocks
__global__ __launch_bounds__(256,2) void gemm_mean(
    const u16* __restrict__ segmean, const u16* __restrict__ wwT, u16* __restrict__ segW)
{
  const int tid=threadIdx.x, lane=tid&63, quad=lane>>4, l15=lane&15;
  const int w=tid>>6, rh=w>>1, chq=w&1;
  const int row0=blockIdx.x*128;
  const int level=row0>>10;
  __shared__ __align__(16) u16 ldsA[128*136];
  #pragma unroll
  for (int it=0; it<8; ++it){
    int row = it*16 + (tid>>4), chn = tid&15;
    *(u32x4*)(&ldsA[row*136 + chn*8]) = *(const u32x4*)(segmean + (size_t)(row0+row)*CCH + chn*8);
  }
  __syncthreads();
  const u16* Bb = wwT + level*16384;
  f32x4 acc[4][4];
  #pragma unroll
  for (int a_=0;a_<4;++a_)
    #pragma unroll
    for (int b_=0;b_<4;++b_) acc[a_][b_]=(f32x4){0.f,0.f,0.f,0.f};
  #pragma unroll
  for (int ks=0; ks<4; ++ks){
    bf16x8 af[4], bfv[4];
    #pragma unroll
    for (int mb=0;mb<4;++mb)
      af[mb]=*(const bf16x8*)(&ldsA[(rh*64+mb*16+l15)*136 + ks*32 + quad*8]);
    #pragma unroll
    for (int nb=0;nb<4;++nb)
      bfv[nb]=*(const bf16x8*)(Bb + (size_t)(chq*64+nb*16+l15)*CCH + ks*32 + quad*8);
    #pragma unroll
    for (int mb=0;mb<4;++mb)
      #pragma unroll
      for (int nb=0;nb<4;++nb)
        acc[mb][nb]=__builtin_amdgcn_mfma_f32_16x16x32_bf16(af[mb],bfv[nb],acc[mb][nb],0,0,0);
  }
  #pragma unroll
  for (int mb=0;mb<4;++mb){
    int rbase=row0+rh*64+mb*16+quad*4;
    #pragma unroll
    for (int e=0;e<4;++e)
      #pragma unroll
      for (int nb=0;nb<4;++nb)
        segW[(size_t)(rbase+e)*CCH + chq*64+nb*16+l15]=f2bf(acc[mb][nb][e]);
  }
}

// ---------------------------------------------------------------- logits GEMM: lrelu(bn(praw)) @ w_w - segW[cluster]
struct LG { const u16* A[3]; float* out[3]; };
__global__ __launch_bounds__(256,2) void gemm_logits(
    LG p, const u16* __restrict__ wwT,
    const float* __restrict__ stats, const float* __restrict__ lwg, const float* __restrict__ lwb,
    const int* __restrict__ clusters, const u16* __restrict__ segW,
    u32* __restrict__ gmax)
{
  const int tid=threadIdx.x, lane=tid&63, quad=lane>>4, l15=lane&15;
  const int w=tid>>6, rh=w>>1, chq=w&1;
  const int row0=blockIdx.x*128;
  const int y=blockIdx.y;

  __shared__ __align__(16) u16 ldsA[128*136];
  __shared__ float tsc[128], tsh[128];
  __shared__ float wred[4];

  if (tid<128){
    const float* st = stats + y*256;
    float s=st[tid], s2=st[128+tid];
    float mean=s*(1.0f/65536.0f);
    float var =s2*(1.0f/65536.0f)-mean*mean;
    float rstd=rsqrtf(var+1e-5f);
    float scv =lwg[y*128+tid]*rstd;
    tsc[tid]=scv; tsh[tid]=lwb[y*128+tid]-mean*scv;
  }
  __syncthreads();

  const u16* Ab = p.A[y];
  #pragma unroll
  for (int it=0; it<8; ++it){
    int row = it*16 + (tid>>4), chn = tid&15;
    u32x4 d = *(const u32x4*)(Ab + (size_t)(row0+row)*CCH + chn*8);
    #pragma unroll
    for (int pq=0;pq<4;++pq){
      u32 xv=d[pq]; int k=chn*8+2*pq;
      float f0=lrelu(tsc[k  ]*bf2f((u16)(xv&0xffffu))+tsh[k  ]);
      float f1=lrelu(tsc[k+1]*bf2f((u16)(xv>>16))    +tsh[k+1]);
      d[pq]=(u32)f2bf(f0)|((u32)f2bf(f1)<<16);
    }
    *(u32x4*)(&ldsA[row*136 + chn*8]) = d;
  }
  __syncthreads();

  const u16* Bb = wwT + y*16384;
  f32x4 acc[4][4];
  #pragma unroll
  for (int a_=0;a_<4;++a_)
    #pragma unroll
    for (int b_=0;b_<4;++b_) acc[a_][b_]=(f32x4){0.f,0.f,0.f,0.f};
  #pragma unroll
  for (int ks=0; ks<4; ++ks){
    bf16x8 af[4], bfv[4];
    #pragma unroll
    for (int mb=0;mb<4;++mb)
      af[mb]=*(const bf16x8*)(&ldsA[(rh*64+mb*16+l15)*136 + ks*32 + quad*8]);
    #pragma unroll
    for (int nb=0;nb<4;++nb)
      bfv[nb]=*(const bf16x8*)(Bb + (size_t)(chq*64+nb*16+l15)*CCH + ks*32 + quad*8);
    #pragma unroll
    for (int mb=0;mb<4;++mb)
      #pragma unroll
      for (int nb=0;nb<4;++nb)
        acc[mb][nb]=__builtin_amdgcn_mfma_f32_16x16x32_bf16(af[mb],bfv[nb],acc[mb][nb],0,0,0);
  }
  float* O = p.out[y];
  float m=-3.0e38f;
  #pragma unroll
  for (int mb=0;mb<4;++mb){
    int rbase=row0+rh*64+mb*16+quad*4;
    #pragma unroll
    for (int e=0;e<4;++e){
      int row=rbase+e;
      int cl=clusters[(size_t)y*NROWS + row];
      const u16* sw = segW + ((size_t)(y*1024+cl))*CCH;
      #pragma unroll
      for (int nb=0;nb<4;++nb){
        int col=chq*64+nb*16+l15;
        float v=acc[mb][nb][e]-bf2f(sw[col]);
        O[(size_t)row*CCH + col]=v;
        m=fmaxf(m,v);
      }
    }
  }
  #pragma unroll
  for (int o=1;o<64;o<<=1) m=fmaxf(m,__shfl_xor(m,o));
  if (lane==0) wred[w]=m;
  __syncthreads();
  if (tid==0){
    float mm=fmaxf(fmaxf(wred[0],wred[1]),fmaxf(wred[2],wred[3]));
    atomicMax(&gmax[y], fenc(mm));
  }
}

// ---------------------------------------------------------------- fuse GEMM: K=256 as 2 taps; tap0 BN+lrelu on staging
__global__ __launch_bounds__(256,2) void gemm_fuse(
    const u16* __restrict__ A0, const u16* __restrict__ A1,
    const float* __restrict__ tstat, const float* __restrict__ tg, const float* __restrict__ tb,
    const u16* __restrict__ BT, u16* __restrict__ out, float* __restrict__ stats)
{
  const int tid=threadIdx.x, lane=tid&63, quad=lane>>4, l15=lane&15;
  const int w=tid>>6, rh=w>>1, chq=w&1;
  const int row0=blockIdx.x*128;

  __shared__ __align__(16) u16 ldsA[128*136];
  __shared__ float tsc[128], tsh[128];
  __shared__ float cs[256];

  if (tid<128){
    float s=tstat[tid], s2=tstat[128+tid];
    float mean=s*(1.0f/65536.0f);
    float var =s2*(1.0f/65536.0f)-mean*mean;
    float rstd=rsqrtf(var+1e-5f);
    float scv =tg[tid]*rstd;
    tsc[tid]=scv; tsh[tid]=tb[tid]-mean*scv;
  }

  f32x4 acc[4][4];
  #pragma unroll
  for (int a_=0;a_<4;++a_)
    #pragma unroll
    for (int b_=0;b_<4;++b_) acc[a_][b_]=(f32x4){0.f,0.f,0.f,0.f};

  #pragma unroll 1
  for (int tap=0; tap<2; ++tap){
    __syncthreads();
    const u16* Ab = tap ? A1 : A0;
    #pragma unroll
    for (int it=0; it<8; ++it){
      int row = it*16 + (tid>>4), chn = tid&15;
      u32x4 d = *(const u32x4*)(Ab + (size_t)(row0+row)*CCH + chn*8);
      if (tap==0){
        #pragma unroll
        for (int pq=0;pq<4;++pq){
          u32 xv=d[pq]; int k=chn*8+2*pq;
          float f0=lrelu(tsc[k  ]*bf2f((u16)(xv&0xffffu))+tsh[k  ]);
          float f1=lrelu(tsc[k+1]*bf2f((u16)(xv>>16))    +tsh[k+1]);
          d[pq]=(u32)f2bf(f0)|((u32)f2bf(f1)<<16);
        }
      }
      *(u32x4*)(&ldsA[row*136 + chn*8]) = d;
    }
    __syncthreads();
    const u16* Bb = BT + tap*128;                 // PB=256, K-offset 128 per tap
    #pragma unroll
    for (int ks=0; ks<4; ++ks){
      bf16x8 af[4], bfv[4];
      #pragma unroll
      for (int mb=0;mb<4;++mb)
        af[mb]=*(const bf16x8*)(&ldsA[(rh*64+mb*16+l15)*136 + ks*32 + quad*8]);
      #pragma unroll
      for (int nb=0;nb<4;++nb)
        bfv[nb]=*(const bf16x8*)(Bb + (size_t)(chq*64+nb*16+l15)*256 + ks*32 + quad*8);
      #pragma unroll
      for (int mb=0;mb<4;++mb)
        #pragma unroll
        for (int nb=0;nb<4;++nb)
          acc[mb][nb]=__builtin_amdgcn_mfma_f32_16x16x32_bf16(af[mb],bfv[nb],acc[mb][nb],0,0,0);
    }
  }
  #pragma unroll
  for (int mb=0;mb<4;++mb){
    int rbase=row0+rh*64+mb*16+quad*4;
    #pragma unroll
    for (int e=0;e<4;++e)
      #pragma unroll
      for (int nb=0;nb<4;++nb)
        out[(size_t)(rbase+e)*CCH + chq*64+nb*16+l15]=f2bf(acc[mb][nb][e]);
  }
  __syncthreads();
  cs[tid]=0.f;
  __syncthreads();
  #pragma unroll
  for (int nb=0;nb<4;++nb){
    float s=0.f,s2=0.f;
    #pragma unroll
    for (int mb=0;mb<4;++mb)
      #pragma unroll
      for (int e=0;e<4;++e){ float v=acc[mb][nb][e]; s+=v; s2+=v*v; }
    s += __shfl_xor(s,16);  s += __shfl_xor(s,32);
    s2+= __shfl_xor(s2,16); s2+= __shfl_xor(s2,32);
    if (lane<16){
      int col=chq*64+nb*16+l15;
      atomicAdd(&cs[col],s); atomicAdd(&cs[128+col],s2);
    }
  }
  __syncthreads();
  atomicAdd(&stats[tid], cs[tid]);
}

// ---------------------------------------------------------------- 27-tap sparse conv: BARRIERLESS fragment-direct
// Wave = 32 rows x 128 cols. A-fragment layout (lane l15=row, quad*8=k-chunk) lets each
// lane gather its 16B of a row STRAIGHT into the A-frag registers -- no LDS staging, no
// per-tap __syncthreads, so the compiler emits per-wave vmcnt(N) waits and 2 taps of
// gathers (~1240 cyc) stay in flight. Fully unrolled 27-tap loop -> static register roles.
// idx prefetched 3 taps ahead. Only barrier: final stats reduction.
__global__ __launch_bounds__(256,2) void conv_k(
    const u16* __restrict__ A, const u16* __restrict__ BT,
    const int* __restrict__ nbrT, u16* __restrict__ out, float* __restrict__ stats)
{
  const int tid=threadIdx.x, lane=tid&63, quad=lane>>4, l15=lane&15;
  const int wv=tid>>6;
  const int row0 = blockIdx.x*128 + wv*32;      // this wave's 32 rows
  __shared__ float cs[256];

  f32x4 acc[2][8];
  #pragma unroll
  for (int mb=0;mb<2;++mb)
    #pragma unroll
    for (int nb=0;nb<8;++nb) acc[mb][nb]=(f32x4){0.f,0.f,0.f,0.f};

  bf16x8 af[3][2][4];   // [set][mb][ks] -- set = tap%3
  int idx[3][2];

  // prologue: idx for taps 0,1,2 ; gathers for taps 0,1
  #pragma unroll
  for (int s=0;s<3;++s)
    #pragma unroll
    for (int mb=0;mb<2;++mb)
      idx[s][mb] = nbrT[(size_t)s*NROWS + row0 + mb*16 + l15];
  #pragma unroll
  for (int s=0;s<2;++s)
    #pragma unroll
    for (int mb=0;mb<2;++mb){
      const u16* rp = A + (size_t)idx[s][mb]*CCH + quad*8;
      #pragma unroll
      for (int ks=0;ks<4;++ks)
        af[s][mb][ks] = *(const bf16x8*)(rp + ks*32);
    }

  #pragma unroll 27
  for (int t=0; t<27; ++t){
    // prefetch idx for tap t+3
    if (t+3<27){
      #pragma unroll
      for (int mb=0;mb<2;++mb)
        idx[(t+3)%3][mb] = nbrT[(size_t)(t+3)*NROWS + row0 + mb*16 + l15];
    }
    // issue gathers for tap t+2 (consumed 2 taps from now)
    if (t+2<27){
      #pragma unroll
      for (int mb=0;mb<2;++mb){
        const u16* rp = A + (size_t)idx[(t+2)%3][mb]*CCH + quad*8;
        #pragma unroll
        for (int ks=0;ks<4;++ks)
          af[(t+2)%3][mb][ks] = *(const bf16x8*)(rp + ks*32);
      }
    }
    // B loads + MFMA for tap t
    const u16* Bb = BT + t*16384;
    #pragma unroll
    for (int ks=0;ks<4;++ks){
      #pragma unroll
      for (int nb=0;nb<8;++nb){
        bf16x8 bfv = *(const bf16x8*)(Bb + (size_t)(nb*16+l15)*CCH + ks*32 + quad*8);
        acc[0][nb]=__builtin_amdgcn_mfma_f32_16x16x32_bf16(af[t%3][0][ks],bfv,acc[0][nb],0,0,0);
        acc[1][nb]=__builtin_amdgcn_mfma_f32_16x16x32_bf16(af[t%3][1][ks],bfv,acc[1][nb],0,0,0);
      }
    }
  }

  // store (C/D: col=lane&15, row=quad*4+reg)
  #pragma unroll
  for (int mb=0;mb<2;++mb){
    int rbase = row0 + mb*16 + quad*4;
    #pragma unroll
    for (int e=0;e<4;++e)
      #pragma unroll
      for (int nb=0;nb<8;++nb)
        out[(size_t)(rbase+e)*CCH + nb*16+l15]=f2bf(acc[mb][nb][e]);
  }

  // stats: block-level LDS reduce then one global atomic per tid
  cs[tid]=0.f;
  __syncthreads();
  #pragma unroll
  for (int nb=0;nb<8;++nb){
    float s=0.f,s2=0.f;
    #pragma unroll
    for (int mb=0;mb<2;++mb)
      #pragma unroll
      for (int e=0;e<4;++e){ float v=acc[mb][nb][e]; s+=v; s2+=v*v; }
    s += __shfl_xor(s,16);  s += __shfl_xor(s,32);
    s2+= __shfl_xor(s2,16); s2+= __shfl_xor(s2,32);
    if (lane<16){
      int col=nb*16+l15;
      atomicAdd(&cs[col],s); atomicAdd(&cs[128+col],s2);
    }
  }
  __syncthreads();
  atomicAdd(&stats[tid], cs[tid]);
}

// ---------------------------------------------------------------- batched per-cluster: softmax + proj*pw cluster-sum
struct F3 { const float* f[3]; };
__global__ __launch_bounds__(256) void seg_softmax_all(
    F3 pw2s, const u16* __restrict__ pfbase,
    const float* __restrict__ stats, const float* __restrict__ gamma, const float* __restrict__ beta,
    const u32* __restrict__ gmax,
    const int* __restrict__ starts, const int* __restrict__ order,
    float* __restrict__ segpf)
{
  __shared__ float sc[128], sh[128], se[128], spf[128];
  const int tid=threadIdx.x, b=blockIdx.x;
  const int level=b>>10, seg=b&1023;
  const float* pw2 = pw2s.f[level];
  const u16* pfraw = pfbase + (size_t)level*PE;
  const float* st = stats + level*256;
  if (tid<128){
    float s=st[tid], s2=st[128+tid];
    float mean=s*(1.0f/65536.0f);
    float var =s2*(1.0f/65536.0f)-mean*mean;
    float rstd=rsqrtf(var+1e-5f);
    float scv =gamma[level*128+tid]*rstd;
    sc[tid]=scv; sh[tid]=beta[level*128+tid]-mean*scv;
    se[tid]=0.f; spf[tid]=0.f;
  }
  __syncthreads();
  const float M = fdec(gmax[level]);
  const int s0=starts[level*1025+seg], en=starts[level*1025+seg+1];
  const int c2=tid&63, half=tid>>6;
  const int* ord = order + level*65536;
  float a0=0.f, a1=0.f;
  for (int m=s0+half; m<en; m+=4){
    int r=ord[m];
    float2 x=*(const float2*)(pw2 + (size_t)r*CCH + 2*c2);
    a0 += __expf(x.x-M); a1 += __expf(x.y-M);
  }
  atomicAdd(&se[2*c2],a0); atomicAdd(&se[2*c2+1],a1);
  __syncthreads();
  const float d0=1.0f/(se[2*c2]+1e-6f), d1=1.0f/(se[2*c2+1]+1e-6f);
  const float sc0=sc[2*c2], sc1=sc[2*c2+1], sh0=sh[2*c2], sh1=sh[2*c2+1];
  float p0=0.f, p1=0.f;
  for (int m=s0+half; m<en; m+=4){
    int r=ord[m];
    float2 x=*(const float2*)(pw2 + (size_t)r*CCH + 2*c2);
    u32 f=*(const u32*)(pfraw + (size_t)r*CCH + 2*c2);
    p0 += lrelu(sc0*bf2f((u16)(f&0xffffu))+sh0) * (__expf(x.x-M)*d0);
    p1 += lrelu(sc1*bf2f((u16)(f>>16))    +sh1) * (__expf(x.y-M)*d1);
  }
  atomicAdd(&spf[2*c2],p0); atomicAdd(&spf[2*c2+1],p1);
  __syncthreads();
  if (tid<128) segpf[(size_t)b*128+tid]=spf[tid];
}

// ---------------------------------------------------------------- adaptive softmax + aggregate
__global__ __launch_bounds__(256) void adp_agg(
    const float* __restrict__ feat, const float* __restrict__ aw,
    const int* __restrict__ clusters, const float* __restrict__ segpf,
    u16* __restrict__ agg)
{
  const int tid=threadIdx.x, w=tid>>6, lane=tid&63;
  const int r = blockIdx.x*4 + w;
  float t0=0.f,t1=0.f,t2=0.f;
  #pragma unroll
  for (int cc=0; cc<2; ++cc){
    int c = lane + cc*64;
    float f=feat[(size_t)r*CCH+c];
    t0 += f*aw[c*3+0];
    t1 += f*aw[c*3+1];
    t2 += f*aw[c*3+2];
  }
  #pragma unroll
  for (int o=1;o<64;o<<=1){
    t0+=__shfl_xor(t0,o); t1+=__shfl_xor(t1,o); t2+=__shfl_xor(t2,o);
  }
  float m=fmaxf(t0,fmaxf(t1,t2));
  float e0=__expf(t0-m), e1=__expf(t1-m), e2=__expf(t2-m);
  float inv=1.0f/(e0+e1+e2);
  float p0=e0*inv,p1=e1*inv,p2=e2*inv;
  int c0=clusters[r], c1_=clusters[NROWS+r], c2_=clusters[2*NROWS+r];
  const float* s0p=segpf + (size_t)c0*128;
  const float* s1p=segpf + (size_t)(1024+c1_)*128;
  const float* s2p=segpf + (size_t)(2048+c2_)*128;
  #pragma unroll
  for (int cc=0; cc<2; ++cc){
    int c = lane + cc*64;
    float v = p0*s0p[c] + p1*s1p[c] + p2*s2p[c];
    agg[(size_t)r*CCH+c]=f2bf(v);
  }
}

// ---------------------------------------------------------------- elementwise BN apply (+residual)
__global__ __launch_bounds__(256) void apply_kernel(
    const u16* __restrict__ raw, const float* __restrict__ stats,
    const float* __restrict__ g_, const float* __restrict__ b_,
    const void* __restrict__ resid, int rf32,
    void* __restrict__ out, int of32,
    int nrows, int mode)
{
  __shared__ float sc[128], sh[128];
  const int tid=threadIdx.x;
  if (tid<128){
    float s=stats[tid], s2=stats[128+tid];
    float mean=s*(1.0f/65536.0f);
    float var =s2*(1.0f/65536.0f)-mean*mean;
    float rstd=rsqrtf(var+1e-5f);
    float scv =g_[tid]*rstd;
    sc[tid]=scv; sh[tid]=b_[tid]-mean*scv;
  }
  __syncthreads();
  size_t chunk = (size_t)blockIdx.x*256 + tid;
  size_t total = (size_t)nrows*16;
  if (chunk >= total) return;
  size_t r = chunk>>4; int c8 = (int)(chunk&15)*8;
  float v[8];
  if (r >= NROWS){
    #pragma unroll
    for (int p=0;p<8;++p) v[p]=0.f;
  } else {
    u32x4 x = *(const u32x4*)(raw + r*CCH + c8);
    float rsd[8];
    if (resid){
      if (rf32){
        const float* R = ((const float*)resid) + r*CCH + c8;
        float4 lo=*(const float4*)R, hi=*(const float4*)(R+4);
        rsd[0]=lo.x; rsd[1]=lo.y; rsd[2]=lo.z; rsd[3]=lo.w;
        rsd[4]=hi.x; rsd[5]=hi.y; rsd[6]=hi.z; rsd[7]=hi.w;
      } else {
        u32x4 rv = *(const u32x4*)(((const u16*)resid) + r*CCH + c8);
        #pragma unroll
        for (int p=0;p<4;++p){
          rsd[2*p]  =bf2f((u16)(rv[p]&0xffffu));
          rsd[2*p+1]=bf2f((u16)(rv[p]>>16));
        }
      }
    } else {
      #pragma unroll
      for (int p=0;p<8;++p) rsd[p]=0.f;
    }
    #pragma unroll
    for (int p=0;p<4;++p){
      u32 xv=x[p];
      int k=c8+2*p;
      float v0=sc[k  ]*bf2f((u16)(xv&0xffffu))+sh[k  ];
      float v1=sc[k+1]*bf2f((u16)(xv>>16))    +sh[k+1];
      if (mode==0){ v[2*p]=lrelu(v0)+rsd[2*p]; v[2*p+1]=lrelu(v1)+rsd[2*p+1]; }
      else        { v[2*p]=lrelu(v0+rsd[2*p]); v[2*p+1]=lrelu(v1+rsd[2*p+1]); }
    }
  }
  if (of32){
    float* O = ((float*)out) + r*CCH + c8;
    float4 lo={v[0],v[1],v[2],v[3]}, hi={v[4],v[5],v[6],v[7]};
    *(float4*)O = lo; *(float4*)(O+4) = hi;
  } else {
    u32x4 o;
    #pragma unroll
    for (int p=0;p<4;++p) o[p] = (u32)f2bf(v[2*p]) | ((u32)f2bf(v[2*p+1])<<16);
    *(u32x4*)(((u16*)out) + r*CCH + c8) = o;
  }
}

// ================================================================ host
extern "C" void kernel_launch(void* const* d_in, const int* in_sizes, int n_in,
                              void* d_out, int out_size, void* d_ws, size_t ws_size,
                              hipStream_t stream)
{
  (void)in_sizes; (void)n_in; (void)out_size; (void)ws_size;
  const float* feat = (const float*)d_in[0];
  const int* clusters = (const int*)d_in[1];
  const int* nbr  = (const int*)d_in[2];
  const float* lw_w = (const float*)d_in[3];
  const float* lw_g = (const float*)d_in[4];
  const float* lw_b = (const float*)d_in[5];
  const float* w_w  = (const float*)d_in[6];
  const float* pj_w = (const float*)d_in[7];
  const float* pj_g = (const float*)d_in[8];
  const float* pj_b = (const float*)d_in[9];
  const float* aw   = (const float*)d_in[10];
  const float* fu_w = (const float*)d_in[11];
  const float* fu_g = (const float*)d_in[12];
  const float* fu_b = (const float*)d_in[13];
  const float* c1w  = (const float*)d_in[14];
  const float* c2w  = (const float*)d_in[15];
  const float* b1g  = (const float*)d_in[16];
  const float* b1b  = (const float*)d_in[17];
  const float* b2g  = (const float*)d_in[18];
  const float* b2b  = (const float*)d_in[19];

  char* wsb = (char*)d_ws;
  u16* WT = (u16*)wsb;                                  // 2,162,688 B
  const size_t o_zero = 2162688;
  float* stats = (float*)(wsb + o_zero);                // 10 x 256 f32
  u32*  gmax   = (u32*) (wsb + o_zero + 10240);         // 3 (+pad)
  int*  cnt    = (int*) (wsb + o_zero + 10496);         // 3x1024
  int*  cur    = (int*) (wsb + o_zero + 22784);         // 3x1024
  u16*  segmean= (u16*) (wsb + o_zero + 35072);         // 3x1024x128 bf16
  u16*  segWb  = (u16*) (wsb + o_zero + 35072 + 786432);// 3x1024x128 bf16
  float* segpf = (float*)(wsb + o_zero + 35072);        // 3x1024x128 f32 (aliases, later)
  const size_t zero_bytes = 22784;                      // stats+gmax+cnt only
  const size_t o_starts = o_zero + 35072 + (size_t)3*1024*128*4;
  int* starts = (int*)(wsb + o_starts);                 // 3x1025 (pad 12544)
  const size_t o_order = o_starts + 12544;
  int* order  = (int*)(wsb + o_order);                  // 3x65536
  const size_t o_pool = o_order + 786432;
  const size_t PE_B = PE*2;                             // 16,777,472 B
  u16* A0=(u16*)(wsb+o_pool + 0*PE_B);   // lw0raw -> fusedB (N+1)
  u16* A1=(u16*)(wsb+o_pool + 1*PE_B);   // lw1raw -> conv1raw
  u16* A2=(u16*)(wsb+o_pool + 2*PE_B);   // lw2raw -> d1 (N+1)
  u16* A3=(u16*)(wsb+o_pool + 3*PE_B);   // pf0raw -> conv2raw
  u16* A4=(u16*)(wsb+o_pool + 4*PE_B);   // pf1raw -> agg
  u16* A5=(u16*)(wsb+o_pool + 5*PE_B);   // pf2raw -> fusedraw
  u16* A6=(u16*)(wsb+o_pool + 6*PE_B);   // flraw
  const size_t o_F = o_pool + 7*PE_B;
  float* F0=(float*)(wsb+o_F);                          // logits lvl0 (f32)
  float* F1=(float*)(wsb+o_F+33554432);                 // lvl1
  float* F2=(float*)d_out;                              // lvl2 logits scratch = d_out
  int* nbrT = (int*)(wsb+o_F);                          // reuses F0 region AFTER seg_softmax

  hipMemsetAsync(wsb+o_zero, 0, zero_bytes, stream);
  prep_transpose<<<4224,256,0,stream>>>(lw_w,w_w,pj_w,fu_w,c1w,c2w,WT);
  hist_k   <<<768,256,0,stream>>>(clusters, cnt);
  scan_k   <<<3,1024,0,stream>>>(cnt, starts, cur);
  scatter_k<<<768,256,0,stream>>>(clusters, cur, order);

  const u16* lwT = WT;
  const u16* wwT = WT + 49152;
  const u16* pjT = WT + 98304;
  const u16* fuT = WT + 163840;
  const u16* c1T = WT + 196608;
  const u16* c2T = WT + 638976;

  float* stLW=stats;         // 3 x 256 (levels 0..2)
  float* stPJ=stats+768;     // 4 x 256 (proj 0..3)
  float* stFU=stats+1792; float* stB1=stats+2048; float* stB2=stats+2304;

  { // phase 1: all 7 feat-GEMMs in one dispatch (A staged once)
    BS7 p;
    for (int i=0;i<3;++i){ p.BT[i]=lwT+i*16384;     p.out[i]=A0+(size_t)i*PE; p.stats[i]=stLW+i*256; }
    for (int i=0;i<4;++i){ p.BT[3+i]=pjT+i*16384;   p.out[3+i]=(i<3)?(A3+(size_t)i*PE):A6; p.stats[3+i]=stPJ+i*256; }
    gemm_feat7<<<512,256,0,stream>>>(feat, p);
  }
  seg_sum_all<<<3072,256,0,stream>>>(A0, stLW, lw_g, lw_b, starts, order, segmean);
  gemm_mean<<<24,256,0,stream>>>(segmean, wwT, segWb);
  {
    LG p;
    float* Fo[3]={F0,F1,F2};
    for (int i=0;i<3;++i){ p.A[i]=A0+(size_t)i*PE; p.out[i]=Fo[i]; }
    gemm_logits<<<dim3(512,3),256,0,stream>>>(p, wwT, stLW, lw_g, lw_b, clusters, segWb, gmax);
  }
  {
    F3 f; f.f[0]=F0; f.f[1]=F1; f.f[2]=F2;
    seg_softmax_all<<<3072,256,0,stream>>>(f, A3, stPJ, pj_g, pj_b, gmax, starts, order, segpf);
  }
  nbrT_k<<<1024,256,0,stream>>>(nbr, nbrT);            // F0 region is dead now
  adp_agg<<<16384,256,0,stream>>>(feat, aw, clusters, segpf, A4);
  gemm_fuse<<<512,256,0,stream>>>(A6, A4, stPJ+768, pj_g+384, pj_b+384, fuT, A5, stFU);
  apply_kernel<<<4097,256,0,stream>>>(A5, stFU, fu_g, fu_b, feat, 1, A0, 0, NROWS+1, 0); // fusedB (zero row N)
  conv_k<<<512,256,0,stream>>>(A0, c1T, nbrT, A1, stB1);
  apply_kernel<<<4097,256,0,stream>>>(A1, stB1, b1g, b1b, nullptr, 0, A2, 0, NROWS+1, 0); // d1 (zero row N)
  conv_k<<<512,256,0,stream>>>(A2, c2T, nbrT, A3, stB2);
  apply_kernel<<<4096,256,0,stream>>>(A3, stB2, b2g, b2b, A0, 0, (float*)d_out, 1, NROWS, 1); // final
}

// Round 7
// 698.951 us; speedup vs baseline: 1.4139x; 1.4139x over previous
//
#include <hip/hip_runtime.h>

typedef unsigned short u16;
typedef unsigned int u32;
typedef __attribute__((ext_vector_type(8))) short bf16x8;   // 8 bf16 in 4 VGPRs
typedef __attribute__((ext_vector_type(4))) float f32x4;
typedef __attribute__((ext_vector_type(4))) u32 u32x4;

#define NROWS 65536
#define CCH 128
#define PE ((size_t)65537*128)     // elems per pool buffer (N+1 rows)

__device__ __forceinline__ float bf2f(u16 x){ u32 u=((u32)x)<<16; return __builtin_bit_cast(float,u); }
__device__ __forceinline__ u16 f2bf(float f){ u32 u=__builtin_bit_cast(u32,f); u += 0x7fffu + ((u>>16)&1u); return (u16)(u>>16); }
__device__ __forceinline__ float lrelu(float v){ return v>=0.f? v : 0.01f*v; }
__device__ __forceinline__ u32 fenc(float f){ u32 u=__builtin_bit_cast(u32,f); return (u & 0x80000000u) ? ~u : (u | 0x80000000u); }
__device__ __forceinline__ float fdec(u32 u){ u32 b = (u & 0x80000000u) ? (u ^ 0x80000000u) : ~u; return __builtin_bit_cast(float,b); }

// ---------------------------------------------------------------- weight transpose (f32 -> bf16 [n][k]) + cluster hist
__global__ __launch_bounds__(256) void prep_transpose(
    const float* __restrict__ lw, const float* __restrict__ ww, const float* __restrict__ pj,
    const float* __restrict__ fw, const float* __restrict__ c1, const float* __restrict__ c2,
    u16* __restrict__ WT, const int* __restrict__ cl, int* __restrict__ cnt)
{
  int i = blockIdx.x*256 + threadIdx.x;   // grid exactly 1081344 threads
  float v;
  if (i < 49152)      { int j=i;        int m=j>>14,e=j&16383,n=e>>7,k=e&127; v=lw[(m<<14)+(k<<7)+n]; }
  else if (i < 98304) { int j=i-49152;  int m=j>>14,e=j&16383,n=e>>7,k=e&127; v=ww[(m<<14)+(k<<7)+n]; }
  else if (i < 163840){ int j=i-98304;  int m=j>>14,e=j&16383,n=e>>7,k=e&127; v=pj[(m<<14)+(k<<7)+n]; }
  else if (i < 196608){ int j=i-163840; int n=j>>8, k=j&255;                  v=fw[(k<<7)+n]; }
  else if (i < 638976){ int j=i-196608; int m=j>>14,e=j&16383,n=e>>7,k=e&127; v=c1[(m<<14)+(k<<7)+n]; }
  else                { int j=i-638976; int m=j>>14,e=j&16383,n=e>>7,k=e&127; v=c2[(m<<14)+(k<<7)+n]; }
  WT[i]=f2bf(v);
  if (i < 196608) atomicAdd(&cnt[(i>>16)*1024 + cl[i]], 1);   // fused CSR hist (3*N)
}

// ---------------------------------------------------------------- CSR scan
__global__ __launch_bounds__(1024) void scan_k(const int* __restrict__ cnt, int* __restrict__ starts, int* __restrict__ cur){
  int l = blockIdx.x, t = threadIdx.x;
  __shared__ int s[1024];
  int v = cnt[l*1024+t];
  s[t]=v; __syncthreads();
  for (int off=1; off<1024; off<<=1){
    int u_ = (t>=off) ? s[t-off] : 0;
    __syncthreads();
    s[t] += u_;
    __syncthreads();
  }
  int incl=s[t], excl=incl-v;
  starts[l*1025+t]=excl;
  if (t==1023) starts[l*1025+1024]=incl;
  cur[l*1024+t]=excl;
}

// ---------------------------------------------------------------- CSR scatter + neighbor transpose (fused, 1024 blocks)
__global__ __launch_bounds__(256) void scatter_nbrT(
    const int* __restrict__ cl, int* __restrict__ cur, int* __restrict__ order,
    const int* __restrict__ nbr, int* __restrict__ nbrT)
{
  __shared__ int s[64*27];
  const int b = blockIdx.x, tid = threadIdx.x;
  int i = b*256 + tid;
  if (i < 196608){                      // scatter (3*N)
    int l = i>>16;
    int c = cl[i];
    int p = atomicAdd(&cur[l*1024+c], 1);
    order[l*65536 + p] = i & 65535;
  }
  for (int j=tid; j<64*27; j+=256) s[j] = nbr[b*64*27 + j];
  __syncthreads();
  for (int j=tid; j<64*27; j+=256){
    int tap=j>>6, row=j&63;
    nbrT[(size_t)tap*NROWS + b*64 + row] = s[row*27 + tap];
  }
}

// ---------------------------------------------------------------- phase-1 GEMM: A=feat (f32) staged once, 7 B-passes
struct BS7 { const u16* BT[7]; u16* out[7]; float* stats[7]; };

__global__ __launch_bounds__(256,2) void gemm_feat7(const float* __restrict__ feat, BS7 p)
{
  const int tid=threadIdx.x, lane=tid&63, quad=lane>>4, l15=lane&15;
  const int w=tid>>6, rh=w>>1, chq=w&1;
  const int row0=blockIdx.x*128;

  __shared__ __align__(16) u16 ldsA[128*136];
  __shared__ float cs[256];

  #pragma unroll
  for (int it=0; it<8; ++it){
    int row = it*16 + (tid>>4), chn = tid&15;
    const float* Af = feat + (size_t)(row0+row)*CCH + chn*8;
    float4 lo = *(const float4*)(Af);
    float4 hi = *(const float4*)(Af+4);
    u32x4 d;
    d[0]=(u32)f2bf(lo.x)|((u32)f2bf(lo.y)<<16);
    d[1]=(u32)f2bf(lo.z)|((u32)f2bf(lo.w)<<16);
    d[2]=(u32)f2bf(hi.x)|((u32)f2bf(hi.y)<<16);
    d[3]=(u32)f2bf(hi.z)|((u32)f2bf(hi.w)<<16);
    *(u32x4*)(&ldsA[row*136 + chn*8]) = d;
  }
  __syncthreads();

  #pragma unroll 1
  for (int y=0; y<7; ++y){
    const u16* Bb = p.BT[y];
    f32x4 acc[4][4];
    #pragma unroll
    for (int a_=0;a_<4;++a_)
      #pragma unroll
      for (int b_=0;b_<4;++b_) acc[a_][b_]=(f32x4){0.f,0.f,0.f,0.f};
    #pragma unroll
    for (int ks=0; ks<4; ++ks){
      bf16x8 af[4], bfv[4];
      #pragma unroll
      for (int mb=0;mb<4;++mb)
        af[mb]=*(const bf16x8*)(&ldsA[(rh*64+mb*16+l15)*136 + ks*32 + quad*8]);
      #pragma unroll
      for (int nb=0;nb<4;++nb)
        bfv[nb]=*(const bf16x8*)(Bb + (size_t)(chq*64+nb*16+l15)*CCH + ks*32 + quad*8);
      #pragma unroll
      for (int mb=0;mb<4;++mb)
        #pragma unroll
        for (int nb=0;nb<4;++nb)
          acc[mb][nb]=__builtin_amdgcn_mfma_f32_16x16x32_bf16(af[mb],bfv[nb],acc[mb][nb],0,0,0);
    }
    u16* O = p.out[y];
    #pragma unroll
    for (int mb=0;mb<4;++mb){
      int rbase=row0+rh*64+mb*16+quad*4;
      #pragma unroll
      for (int e=0;e<4;++e)
        #pragma unroll
        for (int nb=0;nb<4;++nb)
          O[(size_t)(rbase+e)*CCH + chq*64+nb*16+l15]=f2bf(acc[mb][nb][e]);
    }
    __syncthreads();
    cs[tid]=0.f;
    __syncthreads();
    #pragma unroll
    for (int nb=0;nb<4;++nb){
      float s=0.f,s2=0.f;
      #pragma unroll
      for (int mb=0;mb<4;++mb)
        #pragma unroll
        for (int e=0;e<4;++e){ float v=acc[mb][nb][e]; s+=v; s2+=v*v; }
      s += __shfl_xor(s,16);  s += __shfl_xor(s,32);
      s2+= __shfl_xor(s2,16); s2+= __shfl_xor(s2,32);
      if (lane<16){
        int col=chq*64+nb*16+l15;
        atomicAdd(&cs[col],s); atomicAdd(&cs[128+col],s2);
      }
    }
    __syncthreads();
    atomicAdd(&p.stats[y][tid], cs[tid]);
  }
}

// ---------------------------------------------------------------- per-cluster mean of lrelu(bn(praw)) -> segmean (bf16)
__global__ __launch_bounds__(256) void seg_sum_all(
    const u16* __restrict__ pbase, const float* __restrict__ stats,
    const float* __restrict__ gamma, const float* __restrict__ beta,
    const int* __restrict__ starts, const int* __restrict__ order,
    u16* __restrict__ segmean)
{
  __shared__ float sc[128], sh[128], ssum[128];
  const int tid=threadIdx.x, b=blockIdx.x;
  const int level=b>>10, seg=b&1023;
  const u16* praw = pbase + (size_t)level*PE;
  const float* st = stats + level*256;
  if (tid<128){
    float s=st[tid], s2=st[128+tid];
    float mean=s*(1.0f/65536.0f);
    float var =s2*(1.0f/65536.0f)-mean*mean;
    float rstd=rsqrtf(var+1e-5f);
    float scv =gamma[level*128+tid]*rstd;
    sc[tid]=scv; sh[tid]=beta[level*128+tid]-mean*scv;
    ssum[tid]=0.f;
  }
  __syncthreads();
  const int s0=starts[level*1025+seg], en=starts[level*1025+seg+1];
  const int c2=tid&63, half=tid>>6;
  const int* ord = order + level*65536;
  const float sc0=sc[2*c2], sc1=sc[2*c2+1], sh0=sh[2*c2], sh1=sh[2*c2+1];
  float a0=0.f, a1=0.f;
  for (int m=s0+half; m<en; m+=4){
    int r=ord[m];
    u32 x=*(const u32*)(praw + (size_t)r*CCH + 2*c2);
    a0 += lrelu(sc0*bf2f((u16)(x&0xffffu))+sh0);
    a1 += lrelu(sc1*bf2f((u16)(x>>16))    +sh1);
  }
  atomicAdd(&ssum[2*c2],a0); atomicAdd(&ssum[2*c2+1],a1);
  __syncthreads();
  if (tid<128){
    float inv = 1.0f/fmaxf((float)(en-s0),1.0f);
    segmean[(size_t)b*128+tid]=f2bf(ssum[tid]*inv);
  }
}

// ---------------------------------------------------------------- logits GEMM: (lrelu(bn(praw)) - segmean[cl]) @ w_w
// Centering done in STAGING (reference order). bf16 logits out + global max over rounded values.
struct LG { const u16* A[3]; u16* out[3]; };
__global__ __launch_bounds__(256,2) void gemm_logits(
    LG p, const u16* __restrict__ wwT,
    const float* __restrict__ stats, const float* __restrict__ lwg, const float* __restrict__ lwb,
    const int* __restrict__ clusters, const u16* __restrict__ segmean,
    u32* __restrict__ gmax)
{
  const int tid=threadIdx.x, lane=tid&63, quad=lane>>4, l15=lane&15;
  const int w=tid>>6, rh=w>>1, chq=w&1;
  const int row0=blockIdx.x*128;
  const int y=blockIdx.y;

  __shared__ __align__(16) u16 ldsA[128*136];
  __shared__ float tsc[128], tsh[128];
  __shared__ float wred[4];

  if (tid<128){
    const float* st = stats + y*256;
    float s=st[tid], s2=st[128+tid];
    float mean=s*(1.0f/65536.0f);
    float var =s2*(1.0f/65536.0f)-mean*mean;
    float rstd=rsqrtf(var+1e-5f);
    float scv =lwg[y*128+tid]*rstd;
    tsc[tid]=scv; tsh[tid]=lwb[y*128+tid]-mean*scv;
  }
  __syncthreads();

  const u16* Ab = p.A[y];
  const u16* smb = segmean + (size_t)y*1024*128;
  #pragma unroll
  for (int it=0; it<8; ++it){
    int row = it*16 + (tid>>4), chn = tid&15;
    int cl = clusters[(size_t)y*NROWS + row0 + row];
    u32x4 d  = *(const u32x4*)(Ab + (size_t)(row0+row)*CCH + chn*8);
    u32x4 sm = *(const u32x4*)(smb + (size_t)cl*CCH + chn*8);
    #pragma unroll
    for (int pq=0;pq<4;++pq){
      u32 xv=d[pq], sv=sm[pq]; int k=chn*8+2*pq;
      float f0=lrelu(tsc[k  ]*bf2f((u16)(xv&0xffffu))+tsh[k  ]) - bf2f((u16)(sv&0xffffu));
      float f1=lrelu(tsc[k+1]*bf2f((u16)(xv>>16))    +tsh[k+1]) - bf2f((u16)(sv>>16));
      d[pq]=(u32)f2bf(f0)|((u32)f2bf(f1)<<16);
    }
    *(u32x4*)(&ldsA[row*136 + chn*8]) = d;
  }
  __syncthreads();

  const u16* Bb = wwT + y*16384;
  f32x4 acc[4][4];
  #pragma unroll
  for (int a_=0;a_<4;++a_)
    #pragma unroll
    for (int b_=0;b_<4;++b_) acc[a_][b_]=(f32x4){0.f,0.f,0.f,0.f};
  #pragma unroll
  for (int ks=0; ks<4; ++ks){
    bf16x8 af[4], bfv[4];
    #pragma unroll
    for (int mb=0;mb<4;++mb)
      af[mb]=*(const bf16x8*)(&ldsA[(rh*64+mb*16+l15)*136 + ks*32 + quad*8]);
    #pragma unroll
    for (int nb=0;nb<4;++nb)
      bfv[nb]=*(const bf16x8*)(Bb + (size_t)(chq*64+nb*16+l15)*CCH + ks*32 + quad*8);
    #pragma unroll
    for (int mb=0;mb<4;++mb)
      #pragma unroll
      for (int nb=0;nb<4;++nb)
        acc[mb][nb]=__builtin_amdgcn_mfma_f32_16x16x32_bf16(af[mb],bfv[nb],acc[mb][nb],0,0,0);
  }
  u16* O = p.out[y];
  float m=-3.0e38f;
  #pragma unroll
  for (int mb=0;mb<4;++mb){
    int rbase=row0+rh*64+mb*16+quad*4;
    #pragma unroll
    for (int e=0;e<4;++e){
      int row=rbase+e;
      #pragma unroll
      for (int nb=0;nb<4;++nb){
        u16 rv = f2bf(acc[mb][nb][e]);
        O[(size_t)row*CCH + chq*64+nb*16+l15]=rv;
        m=fmaxf(m,bf2f(rv));                 // max over ROUNDED values (self-consistent)
      }
    }
  }
  #pragma unroll
  for (int o=1;o<64;o<<=1) m=fmaxf(m,__shfl_xor(m,o));
  if (lane==0) wred[w]=m;
  __syncthreads();
  if (tid==0){
    float mm=fmaxf(fmaxf(wred[0],wred[1]),fmaxf(wred[2],wred[3]));
    atomicMax(&gmax[y], fenc(mm));
  }
}

// ---------------------------------------------------------------- fuse GEMM: K=256 as 2 taps; tap0 BN+lrelu on staging
__global__ __launch_bounds__(256,2) void gemm_fuse(
    const u16* __restrict__ A0, const u16* __restrict__ A1,
    const float* __restrict__ tstat, const float* __restrict__ tg, const float* __restrict__ tb,
    const u16* __restrict__ BT, u16* __restrict__ out, float* __restrict__ stats)
{
  const int tid=threadIdx.x, lane=tid&63, quad=lane>>4, l15=lane&15;
  const int w=tid>>6, rh=w>>1, chq=w&1;
  const int row0=blockIdx.x*128;

  __shared__ __align__(16) u16 ldsA[128*136];
  __shared__ float tsc[128], tsh[128];
  __shared__ float cs[256];

  if (tid<128){
    float s=tstat[tid], s2=tstat[128+tid];
    float mean=s*(1.0f/65536.0f);
    float var =s2*(1.0f/65536.0f)-mean*mean;
    float rstd=rsqrtf(var+1e-5f);
    float scv =tg[tid]*rstd;
    tsc[tid]=scv; tsh[tid]=tb[tid]-mean*scv;
  }

  f32x4 acc[4][4];
  #pragma unroll
  for (int a_=0;a_<4;++a_)
    #pragma unroll
    for (int b_=0;b_<4;++b_) acc[a_][b_]=(f32x4){0.f,0.f,0.f,0.f};

  #pragma unroll 1
  for (int tap=0; tap<2; ++tap){
    __syncthreads();
    const u16* Ab = tap ? A1 : A0;
    #pragma unroll
    for (int it=0; it<8; ++it){
      int row = it*16 + (tid>>4), chn = tid&15;
      u32x4 d = *(const u32x4*)(Ab + (size_t)(row0+row)*CCH + chn*8);
      if (tap==0){
        #pragma unroll
        for (int pq=0;pq<4;++pq){
          u32 xv=d[pq]; int k=chn*8+2*pq;
          float f0=lrelu(tsc[k  ]*bf2f((u16)(xv&0xffffu))+tsh[k  ]);
          float f1=lrelu(tsc[k+1]*bf2f((u16)(xv>>16))    +tsh[k+1]);
          d[pq]=(u32)f2bf(f0)|((u32)f2bf(f1)<<16);
        }
      }
      *(u32x4*)(&ldsA[row*136 + chn*8]) = d;
    }
    __syncthreads();
    const u16* Bb = BT + tap*128;                 // PB=256, K-offset 128 per tap
    #pragma unroll
    for (int ks=0; ks<4; ++ks){
      bf16x8 af[4], bfv[4];
      #pragma unroll
      for (int mb=0;mb<4;++mb)
        af[mb]=*(const bf16x8*)(&ldsA[(rh*64+mb*16+l15)*136 + ks*32 + quad*8]);
      #pragma unroll
      for (int nb=0;nb<4;++nb)
        bfv[nb]=*(const bf16x8*)(Bb + (size_t)(chq*64+nb*16+l15)*256 + ks*32 + quad*8);
      #pragma unroll
      for (int mb=0;mb<4;++mb)
        #pragma unroll
        for (int nb=0;nb<4;++nb)
          acc[mb][nb]=__builtin_amdgcn_mfma_f32_16x16x32_bf16(af[mb],bfv[nb],acc[mb][nb],0,0,0);
    }
  }
  #pragma unroll
  for (int mb=0;mb<4;++mb){
    int rbase=row0+rh*64+mb*16+quad*4;
    #pragma unroll
    for (int e=0;e<4;++e)
      #pragma unroll
      for (int nb=0;nb<4;++nb)
        out[(size_t)(rbase+e)*CCH + chq*64+nb*16+l15]=f2bf(acc[mb][nb][e]);
  }
  __syncthreads();
  cs[tid]=0.f;
  __syncthreads();
  #pragma unroll
  for (int nb=0;nb<4;++nb){
    float s=0.f,s2=0.f;
    #pragma unroll
    for (int mb=0;mb<4;++mb)
      #pragma unroll
      for (int e=0;e<4;++e){ float v=acc[mb][nb][e]; s+=v; s2+=v*v; }
    s += __shfl_xor(s,16);  s += __shfl_xor(s,32);
    s2+= __shfl_xor(s2,16); s2+= __shfl_xor(s2,32);
    if (lane<16){
      int col=chq*64+nb*16+l15;
      atomicAdd(&cs[col],s); atomicAdd(&cs[128+col],s2);
    }
  }
  __syncthreads();
  atomicAdd(&stats[tid], cs[tid]);
}

// ---------------------------------------------------------------- 27-tap sparse conv (round-4 structure: best measured)
// 128-row tile, LDS dbuf, 1-deep reg prefetch; coalesced 4-rows-per-wave staging.
// Gather path is rate-limited (~3.2 TB/s L2-fill for random 256B rows) — measured floor ~142us.
__global__ __launch_bounds__(256,2) void conv_k(
    const u16* __restrict__ A, const u16* __restrict__ BT,
    const int* __restrict__ nbrT, u16* __restrict__ out, float* __restrict__ stats)
{
  const int tid=threadIdx.x, lane=tid&63, quad=lane>>4, l15=lane&15;
  const int w=tid>>6, rh=w>>1, chq=w&1;
  const int row0=blockIdx.x*128;
  const int srow=tid>>4, schn=tid&15;      // 16 rows/thread-group, 16B chunks

  __shared__ __align__(16) u16 bufA[2][128*136];   // 2 x 34816 B
  __shared__ float cs[256];

  // prologue: stage tap 0 into buf0; preload idx of tap 1 into regs
  u32x4 pre[8];
  int idxn[8];
  #pragma unroll
  for (int it=0; it<8; ++it){
    int arow = nbrT[row0 + it*16 + srow];
    pre[it] = *(const u32x4*)(A + (size_t)arow*CCH + schn*8);
  }
  #pragma unroll
  for (int it=0; it<8; ++it)
    idxn[it] = nbrT[(size_t)NROWS + row0 + it*16 + srow];
  #pragma unroll
  for (int it=0; it<8; ++it)
    *(u32x4*)(&bufA[0][(it*16+srow)*136 + schn*8]) = pre[it];
  __syncthreads();

  f32x4 acc[4][4];
  #pragma unroll
  for (int a_=0;a_<4;++a_)
    #pragma unroll
    for (int b_=0;b_<4;++b_) acc[a_][b_]=(f32x4){0.f,0.f,0.f,0.f};

  #pragma unroll 1
  for (int tap=0; tap<27; ++tap){
    const int cur = tap&1, nxt = cur^1;
    if (tap<26){
      #pragma unroll
      for (int it=0; it<8; ++it)
        pre[it] = *(const u32x4*)(A + (size_t)idxn[it]*CCH + schn*8);
      if (tap<25){
        #pragma unroll
        for (int it=0; it<8; ++it)
          idxn[it] = nbrT[(size_t)(tap+2)*NROWS + row0 + it*16 + srow];
      }
    }
    const u16* Bb = BT + tap*16384;
    #pragma unroll
    for (int ks=0; ks<4; ++ks){
      bf16x8 af[4], bfv[4];
      #pragma unroll
      for (int mb=0;mb<4;++mb)
        af[mb]=*(const bf16x8*)(&bufA[cur][(rh*64+mb*16+l15)*136 + ks*32 + quad*8]);
      #pragma unroll
      for (int nb=0;nb<4;++nb)
        bfv[nb]=*(const bf16x8*)(Bb + (size_t)(chq*64+nb*16+l15)*CCH + ks*32 + quad*8);
      #pragma unroll
      for (int mb=0;mb<4;++mb)
        #pragma unroll
        for (int nb=0;nb<4;++nb)
          acc[mb][nb]=__builtin_amdgcn_mfma_f32_16x16x32_bf16(af[mb],bfv[nb],acc[mb][nb],0,0,0);
    }
    if (tap<26){
      #pragma unroll
      for (int it=0; it<8; ++it)
        *(u32x4*)(&bufA[nxt][(it*16+srow)*136 + schn*8]) = pre[it];
    }
    __syncthreads();
  }

  #pragma unroll
  for (int mb=0;mb<4;++mb){
    int rbase=row0+rh*64+mb*16+quad*4;
    #pragma unroll
    for (int e=0;e<4;++e)
      #pragma unroll
      for (int nb=0;nb<4;++nb)
        out[(size_t)(rbase+e)*CCH + chq*64+nb*16+l15]=f2bf(acc[mb][nb][e]);
  }
  cs[tid]=0.f;
  __syncthreads();
  #pragma unroll
  for (int nb=0;nb<4;++nb){
    float s=0.f,s2=0.f;
    #pragma unroll
    for (int mb=0;mb<4;++mb)
      #pragma unroll
      for (int e=0;e<4;++e){ float v=acc[mb][nb][e]; s+=v; s2+=v*v; }
    s += __shfl_xor(s,16);  s += __shfl_xor(s,32);
    s2+= __shfl_xor(s2,16); s2+= __shfl_xor(s2,32);
    if (lane<16){
      int col=chq*64+nb*16+l15;
      atomicAdd(&cs[col],s); atomicAdd(&cs[128+col],s2);
    }
  }
  __syncthreads();
  atomicAdd(&stats[tid], cs[tid]);
}

// ---------------------------------------------------------------- batched per-cluster: softmax + proj*pw cluster-sum
struct F3 { const u16* f[3]; };
__global__ __launch_bounds__(256) void seg_softmax_all(
    F3 pw2s, const u16* __restrict__ pfbase,
    const float* __restrict__ stats, const float* __restrict__ gamma, const float* __restrict__ beta,
    const u32* __restrict__ gmax,
    const int* __restrict__ starts, const int* __restrict__ order,
    float* __restrict__ segpf)
{
  __shared__ float sc[128], sh[128], se[128], spf[128];
  const int tid=threadIdx.x, b=blockIdx.x;
  const int level=b>>10, seg=b&1023;
  const u16* pw2 = pw2s.f[level];
  const u16* pfraw = pfbase + (size_t)level*PE;
  const float* st = stats + level*256;
  if (tid<128){
    float s=st[tid], s2=st[128+tid];
    float mean=s*(1.0f/65536.0f);
    float var =s2*(1.0f/65536.0f)-mean*mean;
    float rstd=rsqrtf(var+1e-5f);
    float scv =gamma[level*128+tid]*rstd;
    sc[tid]=scv; sh[tid]=beta[level*128+tid]-mean*scv;
    se[tid]=0.f; spf[tid]=0.f;
  }
  __syncthreads();
  const float M = fdec(gmax[level]);
  const int s0=starts[level*1025+seg], en=starts[level*1025+seg+1];
  const int c2=tid&63, half=tid>>6;
  const int* ord = order + level*65536;
  float a0=0.f, a1=0.f;
  for (int m=s0+half; m<en; m+=4){
    int r=ord[m];
    u32 x=*(const u32*)(pw2 + (size_t)r*CCH + 2*c2);
    a0 += __expf(bf2f((u16)(x&0xffffu))-M);
    a1 += __expf(bf2f((u16)(x>>16))   -M);
  }
  atomicAdd(&se[2*c2],a0); atomicAdd(&se[2*c2+1],a1);
  __syncthreads();
  const float d0=1.0f/(se[2*c2]+1e-6f), d1=1.0f/(se[2*c2+1]+1e-6f);
  const float sc0=sc[2*c2], sc1=sc[2*c2+1], sh0=sh[2*c2], sh1=sh[2*c2+1];
  float p0=0.f, p1=0.f;
  for (int m=s0+half; m<en; m+=4){
    int r=ord[m];
    u32 x=*(const u32*)(pw2 + (size_t)r*CCH + 2*c2);
    u32 f=*(const u32*)(pfraw + (size_t)r*CCH + 2*c2);
    p0 += lrelu(sc0*bf2f((u16)(f&0xffffu))+sh0) * (__expf(bf2f((u16)(x&0xffffu))-M)*d0);
    p1 += lrelu(sc1*bf2f((u16)(f>>16))    +sh1) * (__expf(bf2f((u16)(x>>16))   -M)*d1);
  }
  atomicAdd(&spf[2*c2],p0); atomicAdd(&spf[2*c2+1],p1);
  __syncthreads();
  if (tid<128) segpf[(size_t)b*128+tid]=spf[tid];
}

// ---------------------------------------------------------------- adaptive softmax + aggregate
__global__ __launch_bounds__(256) void adp_agg(
    const float* __restrict__ feat, const float* __restrict__ aw,
    const int* __restrict__ clusters, const float* __restrict__ segpf,
    u16* __restrict__ agg)
{
  const int tid=threadIdx.x, w=tid>>6, lane=tid&63;
  const int r = blockIdx.x*4 + w;
  float t0=0.f,t1=0.f,t2=0.f;
  #pragma unroll
  for (int cc=0; cc<2; ++cc){
    int c = lane + cc*64;
    float f=feat[(size_t)r*CCH+c];
    t0 += f*aw[c*3+0];
    t1 += f*aw[c*3+1];
    t2 += f*aw[c*3+2];
  }
  #pragma unroll
  for (int o=1;o<64;o<<=1){
    t0+=__shfl_xor(t0,o); t1+=__shfl_xor(t1,o); t2+=__shfl_xor(t2,o);
  }
  float m=fmaxf(t0,fmaxf(t1,t2));
  float e0=__expf(t0-m), e1=__expf(t1-m), e2=__expf(t2-m);
  float inv=1.0f/(e0+e1+e2);
  float p0=e0*inv,p1=e1*inv,p2=e2*inv;
  int c0=clusters[r], c1_=clusters[NROWS+r], c2_=clusters[2*NROWS+r];
  const float* s0p=segpf + (size_t)c0*128;
  const float* s1p=segpf + (size_t)(1024+c1_)*128;
  const float* s2p=segpf + (size_t)(2048+c2_)*128;
  #pragma unroll
  for (int cc=0; cc<2; ++cc){
    int c = lane + cc*64;
    float v = p0*s0p[c] + p1*s1p[c] + p2*s2p[c];
    agg[(size_t)r*CCH+c]=f2bf(v);
  }
}

// ---------------------------------------------------------------- elementwise BN apply (+residual)
__global__ __launch_bounds__(256) void apply_kernel(
    const u16* __restrict__ raw, const float* __restrict__ stats,
    const float* __restrict__ g_, const float* __restrict__ b_,
    const void* __restrict__ resid, int rf32,
    void* __restrict__ out, int of32,
    int nrows, int mode)
{
  __shared__ float sc[128], sh[128];
  const int tid=threadIdx.x;
  if (tid<128){
    float s=stats[tid], s2=stats[128+tid];
    float mean=s*(1.0f/65536.0f);
    float var =s2*(1.0f/65536.0f)-mean*mean;
    float rstd=rsqrtf(var+1e-5f);
    float scv =g_[tid]*rstd;
    sc[tid]=scv; sh[tid]=b_[tid]-mean*scv;
  }
  __syncthreads();
  size_t chunk = (size_t)blockIdx.x*256 + tid;
  size_t total = (size_t)nrows*16;
  if (chunk >= total) return;
  size_t r = chunk>>4; int c8 = (int)(chunk&15)*8;
  float v[8];
  if (r >= NROWS){
    #pragma unroll
    for (int p=0;p<8;++p) v[p]=0.f;
  } else {
    u32x4 x = *(const u32x4*)(raw + r*CCH + c8);
    float rsd[8];
    if (resid){
      if (rf32){
        const float* R = ((const float*)resid) + r*CCH + c8;
        float4 lo=*(const float4*)R, hi=*(const float4*)(R+4);
        rsd[0]=lo.x; rsd[1]=lo.y; rsd[2]=lo.z; rsd[3]=lo.w;
        rsd[4]=hi.x; rsd[5]=hi.y; rsd[6]=hi.z; rsd[7]=hi.w;
      } else {
        u32x4 rv = *(const u32x4*)(((const u16*)resid) + r*CCH + c8);
        #pragma unroll
        for (int p=0;p<4;++p){
          rsd[2*p]  =bf2f((u16)(rv[p]&0xffffu));
          rsd[2*p+1]=bf2f((u16)(rv[p]>>16));
        }
      }
    } else {
      #pragma unroll
      for (int p=0;p<8;++p) rsd[p]=0.f;
    }
    #pragma unroll
    for (int p=0;p<4;++p){
      u32 xv=x[p];
      int k=c8+2*p;
      float v0=sc[k  ]*bf2f((u16)(xv&0xffffu))+sh[k  ];
      float v1=sc[k+1]*bf2f((u16)(xv>>16))    +sh[k+1];
      if (mode==0){ v[2*p]=lrelu(v0)+rsd[2*p]; v[2*p+1]=lrelu(v1)+rsd[2*p+1]; }
      else        { v[2*p]=lrelu(v0+rsd[2*p]); v[2*p+1]=lrelu(v1+rsd[2*p+1]); }
    }
  }
  if (of32){
    float* O = ((float*)out) + r*CCH + c8;
    float4 lo={v[0],v[1],v[2],v[3]}, hi={v[4],v[5],v[6],v[7]};
    *(float4*)O = lo; *(float4*)(O+4) = hi;
  } else {
    u32x4 o;
    #pragma unroll
    for (int p=0;p<4;++p) o[p] = (u32)f2bf(v[2*p]) | ((u32)f2bf(v[2*p+1])<<16);
    *(u32x4*)(((u16*)out) + r*CCH + c8) = o;
  }
}

// ================================================================ host
extern "C" void kernel_launch(void* const* d_in, const int* in_sizes, int n_in,
                              void* d_out, int out_size, void* d_ws, size_t ws_size,
                              hipStream_t stream)
{
  (void)in_sizes; (void)n_in; (void)out_size; (void)ws_size;
  const float* feat = (const float*)d_in[0];
  const int* clusters = (const int*)d_in[1];
  const int* nbr  = (const int*)d_in[2];
  const float* lw_w = (const float*)d_in[3];
  const float* lw_g = (const float*)d_in[4];
  const float* lw_b = (const float*)d_in[5];
  const float* w_w  = (const float*)d_in[6];
  const float* pj_w = (const float*)d_in[7];
  const float* pj_g = (const float*)d_in[8];
  const float* pj_b = (const float*)d_in[9];
  const float* aw   = (const float*)d_in[10];
  const float* fu_w = (const float*)d_in[11];
  const float* fu_g = (const float*)d_in[12];
  const float* fu_b = (const float*)d_in[13];
  const float* c1w  = (const float*)d_in[14];
  const float* c2w  = (const float*)d_in[15];
  const float* b1g  = (const float*)d_in[16];
  const float* b1b  = (const float*)d_in[17];
  const float* b2g  = (const float*)d_in[18];
  const float* b2b  = (const float*)d_in[19];

  char* wsb = (char*)d_ws;
  u16* WT = (u16*)wsb;                                  // 2,162,688 B
  const size_t o_zero = 2162688;
  float* stats = (float*)(wsb + o_zero);                // 10 x 256 f32 (10240)
  u32*  gmax   = (u32*) (wsb + o_zero + 10240);         // 3 (+pad 256)
  int*  cnt    = (int*) (wsb + o_zero + 10496);         // 3x1024 (12288)
  const size_t zero_bytes = 22784;                      // stats+gmax+cnt
  int*  cur    = (int*) (wsb + o_zero + 22784);         // 3x1024 (scan-written)
  u16*  segmean= (u16*) (wsb + o_zero + 35072);         // 3x1024x128 bf16 (786432)
  float* segpf = (float*)(wsb + o_zero + 821504);       // 3x1024x128 f32 (1572864)
  const size_t o_starts = o_zero + 2394368;
  int* starts = (int*)(wsb + o_starts);                 // 3x1025 (pad 12544)
  const size_t o_order = o_starts + 12544;
  int* order  = (int*)(wsb + o_order);                  // 3x65536 (786432)
  const size_t o_pool = o_order + 786432;
  const size_t PE_B = PE*2;                             // 16,777,472 B
  u16* A0=(u16*)(wsb+o_pool + 0*PE_B);   // lw0raw -> fusedB (N+1)
  u16* A1=(u16*)(wsb+o_pool + 1*PE_B);   // lw1raw -> conv1raw
  u16* A2=(u16*)(wsb+o_pool + 2*PE_B);   // lw2raw -> d1 (N+1)
  u16* A3=(u16*)(wsb+o_pool + 3*PE_B);   // pf0raw -> conv2raw
  u16* A4=(u16*)(wsb+o_pool + 4*PE_B);   // pf1raw -> agg
  u16* A5=(u16*)(wsb+o_pool + 5*PE_B);   // pf2raw -> fusedraw
  u16* A6=(u16*)(wsb+o_pool + 6*PE_B);   // flraw
  const size_t o_F = o_pool + 7*PE_B;
  u16* F0=(u16*)(wsb+o_F);                              // logits lvl0 (bf16, 16.8MB slot)
  u16* F1=(u16*)(wsb+o_F+PE_B);                         // lvl1
  u16* F2=(u16*)d_out;                                  // lvl2 logits scratch = d_out (33.5MB f32 slot)
  int* nbrT = (int*)(wsb+o_F+2*PE_B);                   // dedicated 7.08 MB (lives whole call)

  hipMemsetAsync(wsb+o_zero, 0, zero_bytes, stream);
  prep_transpose<<<4224,256,0,stream>>>(lw_w,w_w,pj_w,fu_w,c1w,c2w,WT, clusters, cnt);
  scan_k<<<3,1024,0,stream>>>(cnt, starts, cur);
  scatter_nbrT<<<1024,256,0,stream>>>(clusters, cur, order, nbr, nbrT);

  const u16* lwT = WT;
  const u16* wwT = WT + 49152;
  const u16* pjT = WT + 98304;
  const u16* fuT = WT + 163840;
  const u16* c1T = WT + 196608;
  const u16* c2T = WT + 638976;

  float* stLW=stats;         // 3 x 256 (levels 0..2)
  float* stPJ=stats+768;     // 4 x 256 (proj 0..3)
  float* stFU=stats+1792; float* stB1=stats+2048; float* stB2=stats+2304;

  { // phase 1: all 7 feat-GEMMs in one dispatch (A staged once)
    BS7 p;
    for (int i=0;i<3;++i){ p.BT[i]=lwT+i*16384;     p.out[i]=A0+(size_t)i*PE; p.stats[i]=stLW+i*256; }
    for (int i=0;i<4;++i){ p.BT[3+i]=pjT+i*16384;   p.out[3+i]=(i<3)?(A3+(size_t)i*PE):A6; p.stats[3+i]=stPJ+i*256; }
    gemm_feat7<<<512,256,0,stream>>>(feat, p);
  }
  seg_sum_all<<<3072,256,0,stream>>>(A0, stLW, lw_g, lw_b, starts, order, segmean);
  {
    LG p;
    u16* Fo[3]={F0,F1,F2};
    for (int i=0;i<3;++i){ p.A[i]=A0+(size_t)i*PE; p.out[i]=Fo[i]; }
    gemm_logits<<<dim3(512,3),256,0,stream>>>(p, wwT, stLW, lw_g, lw_b, clusters, segmean, gmax);
  }
  {
    F3 f; f.f[0]=F0; f.f[1]=F1; f.f[2]=F2;
    seg_softmax_all<<<3072,256,0,stream>>>(f, A3, stPJ, pj_g, pj_b, gmax, starts, order, segpf);
  }
  adp_agg<<<16384,256,0,stream>>>(feat, aw, clusters, segpf, A4);
  gemm_fuse<<<512,256,0,stream>>>(A6, A4, stPJ+768, pj_g+384, pj_b+384, fuT, A5, stFU);
  apply_kernel<<<4097,256,0,stream>>>(A5, stFU, fu_g, fu_b, feat, 1, A0, 0, NROWS+1, 0); // fusedB (zero row N)
  conv_k<<<512,256,0,stream>>>(A0, c1T, nbrT, A1, stB1);
  apply_kernel<<<4097,256,0,stream>>>(A1, stB1, b1g, b1b, nullptr, 0, A2, 0, NROWS+1, 0); // d1 (zero row N)
  conv_k<<<512,256,0,stream>>>(A2, c2T, nbrT, A3, stB2);
  apply_kernel<<<4096,256,0,stream>>>(A3, stB2, b2g, b2b, A0, 0, (float*)d_out, 1, NROWS, 1); // final
}